// Round 1
// baseline (1398.889 us; speedup 1.0000x reference)
//
#include <hip/hip_runtime.h>
#include <stdint.h>

#define NTOK 49
#define DIMC 256
#define HEADS 8
#define SCALE 0.17677669529663687f

typedef __attribute__((ext_vector_type(8))) short bf16x8;
typedef __attribute__((ext_vector_type(4))) float f32x4;

__device__ __forceinline__ unsigned short f2bf(float f) {
    union { float f; unsigned int u; } v; v.f = f;
    unsigned int r = v.u + 0x7FFFu + ((v.u >> 16) & 1u);
    return (unsigned short)(r >> 16);
}

// ---- prep: cast weights to bf16, pregather bias[h][i][j] ----
__global__ void prep_kernel(const float* __restrict__ qkv_w,
                            const float* __restrict__ proj_w,
                            const float* __restrict__ bias_table,
                            unsigned short* __restrict__ w_qkv,
                            unsigned short* __restrict__ w_proj,
                            float* __restrict__ bias_g) {
    const int total = 196608 + 65536 + 19208;
    for (int i = blockIdx.x * blockDim.x + threadIdx.x; i < total;
         i += gridDim.x * blockDim.x) {
        if (i < 196608) {
            w_qkv[i] = f2bf(qkv_w[i]);
        } else if (i < 262144) {
            w_proj[i - 196608] = f2bf(proj_w[i - 196608]);
        } else {
            int idx = i - 262144;
            int h = idx / 2401; int rem = idx - h * 2401;
            int ti = rem / 49;  int tj = rem - ti * 49;
            int ih = ti / 7, iw = ti - (ti / 7) * 7;
            int jh = tj / 7, jw = tj - (tj / 7) * 7;
            int rel = (ih - jh + 6) * 13 + (iw - jw + 6);
            bias_g[idx] = bias_table[rel * 8 + h];
        }
    }
}

// ---- fused window attention: one window per block, 8 waves ----
// LDS layout (bf16 rows padded to 264 elems = 528B => stride%32dw == 4 => 2-way only)
//  sQ  [64][264] bf16   33792 B
//  sK  [64][264] bf16   33792 B
//  sVt [8][32][72] bf16 36864 B   (V transposed: [h][d][token])
//  sS  [64][68] f32     17408 B   (scores / probabilities)
//  sX  [64][264] bf16   33792 B   (x staging; reused as O after QKV)
__global__ __launch_bounds__(512, 2) void wattn_kernel(
    const float* __restrict__ x,
    const float* __restrict__ qkv_b,
    const float* __restrict__ proj_b,
    const unsigned short* __restrict__ w_qkv,
    const unsigned short* __restrict__ w_proj,
    const float* __restrict__ bias_g,
    float* __restrict__ out)
{
    extern __shared__ char smem[];
    unsigned short* sQ  = (unsigned short*)smem;            // 16896 elems
    unsigned short* sK  = sQ + 64 * 264;
    unsigned short* sVt = sK + 64 * 264;                    // 18432 elems
    float*          sS  = (float*)(sVt + 8 * 32 * 72);      // 4352 floats
    unsigned short* sX  = (unsigned short*)(sS + 64 * 68);
    unsigned short* sO  = sX;

    const int b    = blockIdx.x;
    const int tid  = threadIdx.x;
    const int wv   = tid >> 6;
    const int lane = tid & 63;
    const int l16  = lane & 15;
    const int lk   = (lane >> 4) * 8;   // per-lane k offset in A/B frags
    const int rrow = (lane >> 4) * 4;   // per-lane row base in C/D frags

    const f32x4 fzero = {0.f, 0.f, 0.f, 0.f};

    // ---------- Phase 1: stage x -> LDS bf16, zero pad rows ----------
    const float* xb = x + (size_t)b * (NTOK * DIMC);
    for (int it = tid * 4; it < NTOK * DIMC; it += 512 * 4) {
        float4 v = *(const float4*)(xb + it);
        int r = it >> 8, c = it & 255;
        ushort4 u = make_ushort4(f2bf(v.x), f2bf(v.y), f2bf(v.z), f2bf(v.w));
        *(ushort4*)(sX + r * 264 + c) = u;
    }
    for (int it = tid * 4; it < 15 * 256; it += 512 * 4) {
        int r = 49 + (it >> 8), c = it & 255;
        *(ushort4*)(sX + r * 264 + c) = make_ushort4(0, 0, 0, 0);
    }
    __syncthreads();

    // ---------- Phase 2: QKV GEMM (64x768, K=256), wave owns 96 cols ----------
    {
        f32x4 acc[4][6];
        #pragma unroll
        for (int rt = 0; rt < 4; ++rt)
            #pragma unroll
            for (int ct = 0; ct < 6; ++ct) acc[rt][ct] = fzero;

        const int colbase = wv * 96;
        for (int kb = 0; kb < 8; ++kb) {
            const int k0 = kb * 32 + lk;
            bf16x8 a[4];
            #pragma unroll
            for (int rt = 0; rt < 4; ++rt)
                a[rt] = *(const bf16x8*)(sX + (rt * 16 + l16) * 264 + k0);
            #pragma unroll
            for (int ct = 0; ct < 6; ++ct) {
                const int col = colbase + ct * 16 + l16;
                bf16x8 bfrag = *(const bf16x8*)(w_qkv + col * 256 + k0);
                #pragma unroll
                for (int rt = 0; rt < 4; ++rt)
                    acc[rt][ct] = __builtin_amdgcn_mfma_f32_16x16x32_bf16(
                        a[rt], bfrag, acc[rt][ct], 0, 0, 0);
            }
        }
        // epilogue: +bias, cast, scatter to Q/K row-major or V transposed
        #pragma unroll
        for (int ct = 0; ct < 6; ++ct) {
            const int col = colbase + ct * 16 + l16;
            const float bias = qkv_b[col];
            const int t  = col >> 8;
            const int hc = col & 255;
            const int h  = hc >> 5, d = hc & 31;
            #pragma unroll
            for (int rt = 0; rt < 4; ++rt) {
                #pragma unroll
                for (int r = 0; r < 4; ++r) {
                    const int row = rt * 16 + rrow + r;
                    const unsigned short val = f2bf(acc[rt][ct][r] + bias);
                    if (t == 0)      sQ[row * 264 + hc] = val;
                    else if (t == 1) sK[row * 264 + hc] = val;
                    else             sVt[h * 2304 + d * 72 + row] = val;
                }
            }
        }
    }
    __syncthreads();

    // ---------- Phase 3: attention per head ----------
    for (int h = 0; h < HEADS; ++h) {
        // S = Q Kh^T * scale + bias   (16 tiles of 16x16, 2 per wave, K=32)
        #pragma unroll
        for (int s = 0; s < 2; ++s) {
            const int t  = wv * 2 + s;
            const int ti = t >> 2, tj = t & 3;
            bf16x8 a  = *(const bf16x8*)(sQ + (ti * 16 + l16) * 264 + h * 32 + lk);
            bf16x8 bb = *(const bf16x8*)(sK + (tj * 16 + l16) * 264 + h * 32 + lk);
            f32x4 acc = __builtin_amdgcn_mfma_f32_16x16x32_bf16(a, bb, fzero, 0, 0, 0);
            #pragma unroll
            for (int r = 0; r < 4; ++r) {
                const int i = ti * 16 + rrow + r;
                const int j = tj * 16 + l16;
                float sv;
                if (j >= NTOK || i >= NTOK) sv = -1e30f;
                else sv = acc[r] * SCALE + bias_g[h * 2401 + i * 49 + j];
                sS[i * 68 + j] = sv;
            }
        }
        __syncthreads();

        // softmax: 8 threads per row, values kept in regs between passes
        {
            const int r = tid >> 3, sub = tid & 7;
            float v[8];
            float mx = -1e30f;
            #pragma unroll
            for (int m = 0; m < 8; ++m) {
                v[m] = sS[r * 68 + sub + 8 * m];
                mx = fmaxf(mx, v[m]);
            }
            mx = fmaxf(mx, __shfl_xor(mx, 1));
            mx = fmaxf(mx, __shfl_xor(mx, 2));
            mx = fmaxf(mx, __shfl_xor(mx, 4));
            float sum = 0.f;
            #pragma unroll
            for (int m = 0; m < 8; ++m) { v[m] = __expf(v[m] - mx); sum += v[m]; }
            sum += __shfl_xor(sum, 1);
            sum += __shfl_xor(sum, 2);
            sum += __shfl_xor(sum, 4);
            const float inv = 1.0f / sum;
            #pragma unroll
            for (int m = 0; m < 8; ++m) sS[r * 68 + sub + 8 * m] = v[m] * inv;
        }
        __syncthreads();

        // O_h = P Vh  (64x32 out, 8 tiles, 1 per wave, K=64 -> 2 mfma)
        {
            const int rt = wv >> 1, ct = wv & 1;
            f32x4 acc = fzero;
            #pragma unroll
            for (int kk = 0; kk < 2; ++kk) {
                const int j0 = kk * 32 + lk;
                float4 p0 = *(const float4*)(sS + (rt * 16 + l16) * 68 + j0);
                float4 p1 = *(const float4*)(sS + (rt * 16 + l16) * 68 + j0 + 4);
                bf16x8 a;
                a[0] = (short)f2bf(p0.x); a[1] = (short)f2bf(p0.y);
                a[2] = (short)f2bf(p0.z); a[3] = (short)f2bf(p0.w);
                a[4] = (short)f2bf(p1.x); a[5] = (short)f2bf(p1.y);
                a[6] = (short)f2bf(p1.z); a[7] = (short)f2bf(p1.w);
                bf16x8 bb = *(const bf16x8*)(sVt + h * 2304 + (ct * 16 + l16) * 72 + j0);
                acc = __builtin_amdgcn_mfma_f32_16x16x32_bf16(a, bb, acc, 0, 0, 0);
            }
            #pragma unroll
            for (int r = 0; r < 4; ++r) {
                const int row = rt * 16 + rrow + r;
                sO[row * 264 + h * 32 + ct * 16 + l16] = f2bf(acc[r]);
            }
        }
        __syncthreads();
    }

    // ---------- Phase 4: proj GEMM (64x256, K=256), wave owns 32 cols ----------
    {
        f32x4 acc[4][2];
        #pragma unroll
        for (int rt = 0; rt < 4; ++rt)
            #pragma unroll
            for (int c = 0; c < 2; ++c) acc[rt][c] = fzero;

        const int colbase = wv * 32;
        for (int kb = 0; kb < 8; ++kb) {
            const int k0 = kb * 32 + lk;
            bf16x8 a[4];
            #pragma unroll
            for (int rt = 0; rt < 4; ++rt)
                a[rt] = *(const bf16x8*)(sO + (rt * 16 + l16) * 264 + k0);
            #pragma unroll
            for (int c = 0; c < 2; ++c) {
                const int col = colbase + c * 16 + l16;
                bf16x8 bfrag = *(const bf16x8*)(w_proj + col * 256 + k0);
                #pragma unroll
                for (int rt = 0; rt < 4; ++rt)
                    acc[rt][c] = __builtin_amdgcn_mfma_f32_16x16x32_bf16(
                        a[rt], bfrag, acc[rt][c], 0, 0, 0);
            }
        }
        float* ob = out + (size_t)b * (NTOK * DIMC);
        #pragma unroll
        for (int c = 0; c < 2; ++c) {
            const int col = colbase + c * 16 + l16;
            const float pb = proj_b[col];
            #pragma unroll
            for (int rt = 0; rt < 4; ++rt) {
                #pragma unroll
                for (int r = 0; r < 4; ++r) {
                    const int row = rt * 16 + rrow + r;
                    if (row < NTOK) ob[row * 256 + col] = acc[rt][c][r] + pb;
                }
            }
        }
    }
}

extern "C" void kernel_launch(void* const* d_in, const int* in_sizes, int n_in,
                              void* d_out, int out_size, void* d_ws, size_t ws_size,
                              hipStream_t stream) {
    const float* x          = (const float*)d_in[0];
    const float* qkv_w      = (const float*)d_in[1];
    const float* qkv_b      = (const float*)d_in[2];
    const float* proj_w     = (const float*)d_in[3];
    const float* proj_b     = (const float*)d_in[4];
    const float* bias_table = (const float*)d_in[5];

    unsigned short* w_qkv  = (unsigned short*)d_ws;   // 196608 bf16
    unsigned short* w_proj = w_qkv + 196608;          // 65536 bf16
    float*          bias_g = (float*)(w_proj + 65536);// 19208 f32  (total ~587KB)

    prep_kernel<<<256, 256, 0, stream>>>(qkv_w, proj_w, bias_table,
                                         w_qkv, w_proj, bias_g);

    const int SMEM = (64 * 264 * 2) * 2   // sQ + sK
                   + 8 * 32 * 72 * 2      // sVt
                   + 64 * 68 * 4          // sS
                   + 64 * 264 * 2;        // sX / sO    = 155648 B
    hipFuncSetAttribute(reinterpret_cast<const void*>(wattn_kernel),
                        hipFuncAttributeMaxDynamicSharedMemorySize, SMEM);

    wattn_kernel<<<8192, 512, SMEM, stream>>>(x, qkv_b, proj_b,
                                              w_qkv, w_proj, bias_g,
                                              (float*)d_out);
}

// Round 2
// 720.096 us; speedup vs baseline: 1.9426x; 1.9426x over previous
//
#include <hip/hip_runtime.h>
#include <hip/hip_bf16.h>
#include <stdint.h>

#define NTOK 49
#define SCALE 0.17677669529663687f

typedef __attribute__((ext_vector_type(8))) short bf16x8;
typedef __attribute__((ext_vector_type(4))) float f32x4;

__device__ __forceinline__ unsigned short f2bf(float f) {
    union { float f; unsigned int u; } v; v.f = f;
    unsigned int r = v.u + 0x7FFFu + ((v.u >> 16) & 1u);
    return (unsigned short)(r >> 16);
}

__device__ __forceinline__ uint32_t pkbf(float lo, float hi) {
    __hip_bfloat162 h = __float22bfloat162_rn(float2{lo, hi});
    union { __hip_bfloat162 h; uint32_t u; } c; c.h = h;
    return c.u;
}

// ---- prep: bf16 weights (Q rows pre-scaled), transposed+masked bias table,
// ---- scaled qkv bias copy ----
__global__ void prep_kernel(const float* __restrict__ qkv_w,
                            const float* __restrict__ proj_w,
                            const float* __restrict__ bias_table,
                            const float* __restrict__ qkv_b,
                            unsigned short* __restrict__ w_qkv,
                            unsigned short* __restrict__ w_proj,
                            float* __restrict__ bias_t,
                            float* __restrict__ sbias) {
    const int total = 196608 + 65536 + 32768 + 768;
    for (int i = blockIdx.x * blockDim.x + threadIdx.x; i < total;
         i += gridDim.x * blockDim.x) {
        if (i < 196608) {
            // rows 0..255 are Q -> fold in SCALE
            float s = (i < 65536) ? SCALE : 1.0f;
            w_qkv[i] = f2bf(qkv_w[i] * s);
        } else if (i < 262144) {
            w_proj[i - 196608] = f2bf(proj_w[i - 196608]);
        } else if (i < 294912) {
            int idx = i - 262144;
            int hh = idx >> 12;             // head
            int j  = (idx >> 6) & 63;       // key token (row)
            int ii = idx & 63;              // query token (col)
            float v;
            if (j >= NTOK)       v = -1e30f;            // mask padded keys
            else if (ii >= NTOK) v = 0.0f;              // garbage queries: finite
            else {
                int rel = (ii / 7 - j / 7 + 6) * 13 + (ii % 7 - j % 7 + 6);
                v = bias_table[rel * 8 + hh];
            }
            bias_t[idx] = v;
        } else {
            int r = i - 294912;
            sbias[r] = qkv_b[r] * (r < 256 ? SCALE : 1.0f);
        }
    }
}

// ---- fused window attention: one window/block, 8 waves, 1 head/wave ----
// LDS: sX [64][264] bf16 (33792 B, reused as sO) + per-wave scratch [32][72]
// bf16 (4608 B x 8 = 36864 B). Total 70656 B -> 2 blocks/CU if VGPR<=128.
__global__ __launch_bounds__(512, 4) void wattn_kernel(
    const float* __restrict__ x,
    const unsigned short* __restrict__ w_qkv,
    const unsigned short* __restrict__ w_proj,
    const float* __restrict__ bias_t,
    const float* __restrict__ sbias,
    const float* __restrict__ proj_b,
    float* __restrict__ out)
{
    extern __shared__ char smem[];
    unsigned short* sX = (unsigned short*)smem;       // 64*264 elems
    unsigned short* scrBase = sX + 64 * 264;

    const int tid  = threadIdx.x;
    const int wv   = tid >> 6;
    const int lane = tid & 63;
    const int l16  = lane & 15;
    const int g    = lane >> 4;
    const int lk   = g * 8;

    unsigned short* scr = scrBase + wv * (32 * 72);
    unsigned short* sO  = sX;
    const int b = blockIdx.x;
    const int h = wv;
    const f32x4 fz = {0.f, 0.f, 0.f, 0.f};

    // ---------- stage x -> LDS bf16, zero pad rows ----------
    const float* xb = x + (size_t)b * (NTOK * 256);
    for (int it = tid * 4; it < NTOK * 256; it += 512 * 4) {
        float4 v = *(const float4*)(xb + it);
        int r = it >> 8, c = it & 255;
        uint2 u = make_uint2(pkbf(v.x, v.y), pkbf(v.z, v.w));
        *(uint2*)(sX + r * 264 + c) = u;
    }
    for (int it = tid * 4; it < 15 * 256; it += 512 * 4) {
        int r = 49 + (it >> 8), c = it & 255;
        *(uint2*)(sX + r * 264 + c) = make_uint2(0, 0);
    }
    __syncthreads();

    bf16x8 qf[4], kf[4], vf[2][2];

    // ---------- QK-GEMM (transposed: C = [Q;K]^T, 64x64) ----------
    {
        f32x4 acc[4][4];
        #pragma unroll
        for (int mt = 0; mt < 4; ++mt)
            #pragma unroll
            for (int nt = 0; nt < 4; ++nt) acc[mt][nt] = fz;

        for (int kb = 0; kb < 8; ++kb) {
            bf16x8 bx[4];
            #pragma unroll
            for (int nt = 0; nt < 4; ++nt)
                bx[nt] = *(const bf16x8*)(sX + (nt * 16 + l16) * 264 + kb * 32 + lk);
            #pragma unroll
            for (int mt = 0; mt < 4; ++mt) {
                const int row = (mt < 2) ? (h * 32 + mt * 16 + l16)
                                         : (256 + h * 32 + (mt - 2) * 16 + l16);
                bf16x8 aw = *(const bf16x8*)(w_qkv + row * 256 + kb * 32 + lk);
                #pragma unroll
                for (int nt = 0; nt < 4; ++nt)
                    acc[mt][nt] = __builtin_amdgcn_mfma_f32_16x16x32_bf16(
                        aw, bx[nt], acc[mt][nt], 0, 0, 0);
            }
        }
        // Q bias (pre-scaled); K bias dropped (softmax-invariant)
        float4 bq0 = *(const float4*)(sbias + h * 32 + 4 * g);
        float4 bq1 = *(const float4*)(sbias + h * 32 + 16 + 4 * g);
        #pragma unroll
        for (int nt = 0; nt < 4; ++nt) {
            acc[0][nt][0] += bq0.x; acc[0][nt][1] += bq0.y;
            acc[0][nt][2] += bq0.z; acc[0][nt][3] += bq0.w;
            acc[1][nt][0] += bq1.x; acc[1][nt][1] += bq1.y;
            acc[1][nt][2] += bq1.z; acc[1][nt][3] += bq1.w;
        }
        // extract Q/K fragments via per-wave LDS bounce (2 token batches)
        #pragma unroll
        for (int bt = 0; bt < 2; ++bt) {
            #pragma unroll
            for (int mt = 0; mt < 4; ++mt) {
                #pragma unroll
                for (int ntl = 0; ntl < 2; ++ntl) {
                    const int nt = bt * 2 + ntl;
                    uint2 d = make_uint2(pkbf(acc[mt][nt][0], acc[mt][nt][1]),
                                         pkbf(acc[mt][nt][2], acc[mt][nt][3]));
                    *(uint2*)(scr + (ntl * 16 + l16) * 72 + mt * 16 + 4 * g) = d;
                }
            }
            #pragma unroll
            for (int ntl = 0; ntl < 2; ++ntl) {
                qf[bt * 2 + ntl] = *(const bf16x8*)(scr + (ntl * 16 + l16) * 72 + lk);
                kf[bt * 2 + ntl] = *(const bf16x8*)(scr + (ntl * 16 + l16) * 72 + 32 + lk);
            }
        }
    }

    // ---------- V-GEMM (normal: C = V, 64 tok x 32 d) ----------
    {
        f32x4 acc[4][2];
        #pragma unroll
        for (int rt = 0; rt < 4; ++rt) { acc[rt][0] = fz; acc[rt][1] = fz; }

        for (int kb = 0; kb < 8; ++kb) {
            bf16x8 ax[4];
            #pragma unroll
            for (int rt = 0; rt < 4; ++rt)
                ax[rt] = *(const bf16x8*)(sX + (rt * 16 + l16) * 264 + kb * 32 + lk);
            #pragma unroll
            for (int ct = 0; ct < 2; ++ct) {
                bf16x8 bw = *(const bf16x8*)(w_qkv + (512 + h * 32 + ct * 16 + l16) * 256 + kb * 32 + lk);
                #pragma unroll
                for (int rt = 0; rt < 4; ++rt)
                    acc[rt][ct] = __builtin_amdgcn_mfma_f32_16x16x32_bf16(
                        ax[rt], bw, acc[rt][ct], 0, 0, 0);
            }
        }
        // extract V^T fragments ([d][token] layout in scratch)
        #pragma unroll
        for (int rt = 0; rt < 4; ++rt)
            #pragma unroll
            for (int ct = 0; ct < 2; ++ct) {
                uint2 d = make_uint2(pkbf(acc[rt][ct][0], acc[rt][ct][1]),
                                     pkbf(acc[rt][ct][2], acc[rt][ct][3]));
                *(uint2*)(scr + (ct * 16 + l16) * 72 + rt * 16 + 4 * g) = d;
            }
        #pragma unroll
        for (int dm = 0; dm < 2; ++dm)
            #pragma unroll
            for (int kk = 0; kk < 2; ++kk)
                vf[dm][kk] = *(const bf16x8*)(scr + (dm * 16 + l16) * 72 + kk * 32 + lk);
    }
    __syncthreads();   // all sX reads done; sO overlay now safe

    // ---------- attention (barrier-free, per-wave head), 2 query halves ----------
    const float* bt_h = bias_t + h * 4096;
    float4 bv0 = *(const float4*)(sbias + 512 + h * 32 + 4 * g);
    float4 bv1 = *(const float4*)(sbias + 512 + h * 32 + 16 + 4 * g);

    #pragma unroll
    for (int hf = 0; hf < 2; ++hf) {
        // S^T acc init from pre-masked bias, then 8 mfma
        f32x4 s[4][2];
        #pragma unroll
        for (int tr = 0; tr < 4; ++tr)
            #pragma unroll
            for (int tl = 0; tl < 2; ++tl) {
                const int i = (hf * 2 + tl) * 16 + l16;
                #pragma unroll
                for (int r = 0; r < 4; ++r)
                    s[tr][tl][r] = bt_h[(tr * 16 + 4 * g + r) * 64 + i];
            }
        #pragma unroll
        for (int tr = 0; tr < 4; ++tr)
            #pragma unroll
            for (int tl = 0; tl < 2; ++tl)
                s[tr][tl] = __builtin_amdgcn_mfma_f32_16x16x32_bf16(
                    kf[tr], qf[hf * 2 + tl], s[tr][tl], 0, 0, 0);

        // column-i softmax: 16 local values + 2 shfl_xor per reduce
        float inv[2];
        #pragma unroll
        for (int tl = 0; tl < 2; ++tl) {
            float mx = s[0][tl][0];
            #pragma unroll
            for (int tr = 0; tr < 4; ++tr)
                #pragma unroll
                for (int r = 0; r < 4; ++r) mx = fmaxf(mx, s[tr][tl][r]);
            mx = fmaxf(mx, __shfl_xor(mx, 16));
            mx = fmaxf(mx, __shfl_xor(mx, 32));
            float sum = 0.f;
            #pragma unroll
            for (int tr = 0; tr < 4; ++tr)
                #pragma unroll
                for (int r = 0; r < 4; ++r) {
                    float e = __expf(s[tr][tl][r] - mx);
                    s[tr][tl][r] = e; sum += e;
                }
            sum += __shfl_xor(sum, 16);
            sum += __shfl_xor(sum, 32);
            inv[tl] = 1.0f / sum;
        }

        // pack P -> scratch [i][j], read back as A-fragments
        #pragma unroll
        for (int tr = 0; tr < 4; ++tr)
            #pragma unroll
            for (int tl = 0; tl < 2; ++tl) {
                uint2 d = make_uint2(pkbf(s[tr][tl][0], s[tr][tl][1]),
                                     pkbf(s[tr][tl][2], s[tr][tl][3]));
                *(uint2*)(scr + (tl * 16 + l16) * 72 + tr * 16 + 4 * g) = d;
            }
        bf16x8 pf[2][2];
        #pragma unroll
        for (int tl = 0; tl < 2; ++tl)
            #pragma unroll
            for (int kk = 0; kk < 2; ++kk)
                pf[tl][kk] = *(const bf16x8*)(scr + (tl * 16 + l16) * 72 + kk * 32 + lk);

        // O^T = V^T P  (unnormalized P; scale by inv afterwards)
        f32x4 o[2][2];
        #pragma unroll
        for (int dm = 0; dm < 2; ++dm) { o[dm][0] = fz; o[dm][1] = fz; }
        #pragma unroll
        for (int dm = 0; dm < 2; ++dm)
            #pragma unroll
            for (int tl = 0; tl < 2; ++tl)
                #pragma unroll
                for (int kk = 0; kk < 2; ++kk)
                    o[dm][tl] = __builtin_amdgcn_mfma_f32_16x16x32_bf16(
                        vf[dm][kk], pf[tl][kk], o[dm][tl], 0, 0, 0);

        // epilogue: *inv, +bv, pack, write O rows into sO
        #pragma unroll
        for (int dm = 0; dm < 2; ++dm) {
            const float4 bv = dm ? bv1 : bv0;
            #pragma unroll
            for (int tl = 0; tl < 2; ++tl) {
                const float iv = inv[tl];
                float r0 = o[dm][tl][0] * iv + bv.x;
                float r1 = o[dm][tl][1] * iv + bv.y;
                float r2 = o[dm][tl][2] * iv + bv.z;
                float r3 = o[dm][tl][3] * iv + bv.w;
                uint2 d = make_uint2(pkbf(r0, r1), pkbf(r2, r3));
                *(uint2*)(sO + ((hf * 2 + tl) * 16 + l16) * 264 + h * 32 + dm * 16 + 4 * g) = d;
            }
        }
    }
    __syncthreads();

    // ---------- proj GEMM (64x256, K=256), wave owns 32 cols ----------
    {
        f32x4 acc[4][2];
        #pragma unroll
        for (int rt = 0; rt < 4; ++rt) { acc[rt][0] = fz; acc[rt][1] = fz; }

        const int colbase = wv * 32;
        for (int kb = 0; kb < 8; ++kb) {
            bf16x8 a[4];
            #pragma unroll
            for (int rt = 0; rt < 4; ++rt)
                a[rt] = *(const bf16x8*)(sO + (rt * 16 + l16) * 264 + kb * 32 + lk);
            #pragma unroll
            for (int c = 0; c < 2; ++c) {
                bf16x8 bw = *(const bf16x8*)(w_proj + (colbase + c * 16 + l16) * 256 + kb * 32 + lk);
                #pragma unroll
                for (int rt = 0; rt < 4; ++rt)
                    acc[rt][c] = __builtin_amdgcn_mfma_f32_16x16x32_bf16(
                        a[rt], bw, acc[rt][c], 0, 0, 0);
            }
        }
        float* ob = out + (size_t)b * (NTOK * 256);
        #pragma unroll
        for (int c = 0; c < 2; ++c) {
            const int col = colbase + c * 16 + l16;
            const float pb = proj_b[col];
            #pragma unroll
            for (int rt = 0; rt < 4; ++rt)
                #pragma unroll
                for (int r = 0; r < 4; ++r) {
                    const int row = rt * 16 + 4 * g + r;
                    if (row < NTOK) ob[row * 256 + col] = acc[rt][c][r] + pb;
                }
        }
    }
}

extern "C" void kernel_launch(void* const* d_in, const int* in_sizes, int n_in,
                              void* d_out, int out_size, void* d_ws, size_t ws_size,
                              hipStream_t stream) {
    const float* x          = (const float*)d_in[0];
    const float* qkv_w      = (const float*)d_in[1];
    const float* qkv_b      = (const float*)d_in[2];
    const float* proj_w     = (const float*)d_in[3];
    const float* proj_b     = (const float*)d_in[4];
    const float* bias_table = (const float*)d_in[5];

    unsigned short* w_qkv  = (unsigned short*)d_ws;      // 196608 bf16
    unsigned short* w_proj = w_qkv + 196608;             // 65536 bf16
    float*          bias_t = (float*)(w_proj + 65536);   // 32768 f32
    float*          sbias  = bias_t + 32768;             // 768 f32

    prep_kernel<<<288, 256, 0, stream>>>(qkv_w, proj_w, bias_table, qkv_b,
                                         w_qkv, w_proj, bias_t, sbias);

    const int SMEM = (64 * 264 + 8 * 32 * 72) * 2;       // 70656 B
    hipFuncSetAttribute(reinterpret_cast<const void*>(wattn_kernel),
                        hipFuncAttributeMaxDynamicSharedMemorySize, SMEM);

    wattn_kernel<<<8192, 512, SMEM, stream>>>(x, w_qkv, w_proj, bias_t, sbias,
                                              proj_b, (float*)d_out);
}